// Round 11
// baseline (116.735 us; speedup 1.0000x reference)
//
#include <hip/hip_runtime.h>
#include <hip/hip_bf16.h>

typedef unsigned short ushort_t;
using f32x4  = __attribute__((ext_vector_type(4))) float;
using f32x16 = __attribute__((ext_vector_type(16))) float;
using bf16x8 = __attribute__((ext_vector_type(8))) short;
typedef unsigned uint2v __attribute__((ext_vector_type(2)));

#define N_PIX 4096

static __device__ __forceinline__ unsigned short f2bf(float f) {
  unsigned int u = __builtin_bit_cast(unsigned int, f);
  u += 0x7FFFu + ((u >> 16) & 1u);   // round-to-nearest-even
  return (unsigned short)(u >> 16);
}
static __device__ __forceinline__ float bf2f(unsigned int us) {
  return __builtin_bit_cast(float, us << 16);
}

typedef union {
  uint4 u4;
  unsigned u[4];
  unsigned long long q[2];
  bf16x8 v;
  unsigned short us[8];
} fragU;

#define LDS_U32(p) ((unsigned)(uintptr_t)((__attribute__((address_space(3))) void*)(p)))

// OP partial slices (1 MB each, 16 total) live in regions dead during the
// attention phase: arena slices 0-8 and the fusBF region (zeroed only AFTER
// flash) slices 9-15. ML in the dead ex-cam_enc region.
static __device__ __forceinline__ size_t op_off(int s) {
  return (s < 9) ? ((size_t)s << 20) : ((size_t)23200512u + ((size_t)(s - 9) << 20));
}
#define ML_OFF 15728640u   // [2a][4split][4096] float2 = 256 KB

// ---------------------------------------------------------------------------
__global__ __launch_bounds__(256) void zero_span_k(uint4* __restrict__ p, int n16) {
  int i = blockIdx.x * 256 + threadIdx.x;
  if (i < n16) p[i] = (uint4){0u, 0u, 0u, 0u};
}

// ---------------------------------------------------------------------------
// prep_k: fused weight pack + input convert.
// ---------------------------------------------------------------------------
__global__ __launch_bounds__(256) void prep_k(
    const float* __restrict__ cam_enc_w, const float* __restrict__ fuser_w,
    const float* __restrict__ lid_proj_w, const float* __restrict__ cam_proj_w,
    const float* __restrict__ lid_qk_w, const float* __restrict__ cam_qk_w,
    const float* __restrict__ cam_v_w, const float* __restrict__ lid_v_w,
    const float* __restrict__ cam_bev, const float* __restrict__ lidar_bev,
    ushort_t* __restrict__ Wp_c, ushort_t* __restrict__ Wp_f,
    ushort_t* __restrict__ Wp_lid, ushort_t* __restrict__ Wp_cam,
    ushort_t* __restrict__ Wq,
    ushort_t* __restrict__ cm, ushort_t* __restrict__ ch_,
    ushort_t* __restrict__ lidBF) {
  const float QSCALE = 0.08908708063747479f * 1.4426950408889634f;
  int idx = blockIdx.x * 256 + threadIdx.x;
  if (idx < 110592) {                     // 9*128*96
    int kk = idx / 12288, r = idx % 12288;
    int co = r / 96, ci = r % 96;
    float v = (co < 126 && ci < 80) ? cam_enc_w[(co * 80 + ci) * 9 + kk] : 0.f;
    Wp_c[idx] = f2bf(v);
  } else if (idx < 700416) {              // 9*128*512
    int j = idx - 110592;
    int kk = j / 65536, r = j % 65536;
    int co = r / 512, ci = r % 512;
    float v = (co < 126 && ci < 504) ? fuser_w[(co * 504 + ci) * 9 + kk] : 0.f;
    Wp_f[j] = f2bf(v);
  } else if (idx < 716800) {              // 128*128
    int j = idx - 700416;
    int co = j >> 7, k = j & 127;
    Wp_lid[j] = f2bf(co < 126 ? lid_proj_w[co * 128 + k] : 0.f);
  } else if (idx < 733184) {
    int j = idx - 716800;
    int co = j >> 7, k = j & 127;
    Wp_cam[j] = f2bf(co < 126 ? cam_proj_w[co * 128 + k] : 0.f);
  } else if (idx < 831488) {              // 6*128*128
    int j = idx - 733184;
    int t = j >> 14, r = j & 16383;
    int row = r >> 7, ci = r & 127;
    float v = 0.f;
    if (ci < 126) {
      if (t == 0)      v = lid_qk_w[row * 126 + ci] * QSCALE;
      else if (t == 1) v = lid_qk_w[(128 + row) * 126 + ci];
      else if (t == 2) v = cam_qk_w[row * 126 + ci] * QSCALE;
      else if (t == 3) v = cam_qk_w[(128 + row) * 126 + ci];
      else if (t == 4) v = cam_v_w[row * 126 + ci];
      else             v = lid_v_w[row * 126 + ci];
    }
    Wq[j] = f2bf(v);
  } else {
    int k = idx - 831488;
    if (k < 327680) {                     // 80*4096 cam
      int ch = k >> 12, n = k & 4095;
      int y = n >> 6, x = n & 63;
      unsigned short b = f2bf(cam_bev[k]);
      cm[ch * 4224 + (y + 1) * 64 + x] = b;
      ch_[ch * 4356 + (y + 1) * 66 + (x + 1)] = b;
    } else {
      int j = k - 327680;                 // 126*4096 lidar
      if (j < 516096) lidBF[j] = f2bf(lidar_bev[j]);
    }
  }
}

// ---------------------------------------------------------------------------
// conv_mfma: implicit-GEMM 3x3 conv, one (ky,kx) tap per blockIdx.y. bf16 parts.
// ---------------------------------------------------------------------------
__global__ __launch_bounds__(256) void conv_mfma_k(
    const ushort_t* __restrict__ Amain,   // [CIp][66][64]
    const ushort_t* __restrict__ Ahalo,   // [CIp][66][66]
    const ushort_t* __restrict__ Wp,      // [9][128][CIp]
    ushort_t* __restrict__ parts,
    int CIp, int ksteps) {
  __shared__ __align__(16) ushort_t Abuf[2][2048];
  const int y   = blockIdx.x;
  const int kk  = blockIdx.y;
  const int ky  = kk / 3, kx = kk - ky * 3;
  const int tid = threadIdx.x;
  const int w   = tid >> 6, l = tid & 63;
  const int lane15 = l & 15, g = l >> 4;
  const int yy1 = y + ky;

  const int ci_l = w * 8 + (l >> 5) * 4 + ((l & 7) >> 1);
  const int m0   = ((l >> 3) & 3) * 16 + (l & 1) * 8;
  const ushort_t* src;
  size_t plane;
  if (kx == 1) { plane = 66 * 64; src = Amain + (size_t)ci_l * plane + yy1 * 64 + m0; }
  else         { plane = 66 * 66; src = Ahalo + (size_t)ci_l * plane + yy1 * 66 + m0 + kx; }

  const ushort_t* wbase = Wp + ((size_t)kk * 128 + w * 32 + lane15) * CIp + g * 8;
  const unsigned tr_base = LDS_U32(&Abuf[0][0]) + (unsigned)(g * 1024 + lane15 * 8);

  f32x4 acc[4][2];
  #pragma unroll
  for (int q = 0; q < 4; ++q) {
    acc[q][0] = (f32x4){0.f, 0.f, 0.f, 0.f};
    acc[q][1] = (f32x4){0.f, 0.f, 0.f, 0.f};
  }

  __builtin_amdgcn_global_load_lds(
      (const __attribute__((address_space(1))) unsigned*)src,
      (__attribute__((address_space(3))) unsigned*)(&Abuf[0][w * 512]), 16, 0, 0);
  __syncthreads();

  for (int s = 0; s < ksteps; ++s) {
    if (s + 1 < ksteps) {
      const ushort_t* srcn = src + (size_t)(s + 1) * 32 * plane;
      __builtin_amdgcn_global_load_lds(
          (const __attribute__((address_space(1))) unsigned*)srcn,
          (__attribute__((address_space(3))) unsigned*)(&Abuf[(s + 1) & 1][w * 512]), 16, 0, 0);
    }
    const ushort_t* wb = wbase + s * 32;
    fragU fb0, fb1;
    fb0.u4 = *(const uint4*)(wb);
    fb1.u4 = *(const uint4*)(wb + 16 * CIp);

    unsigned ta = tr_base + (unsigned)((s & 1) << 12);
    unsigned long long r00, r01, r10, r11, r20, r21, r30, r31;
    asm volatile("ds_read_b64_tr_b16 %0, %1 offset:0"   : "=v"(r00) : "v"(ta));
    asm volatile("ds_read_b64_tr_b16 %0, %1 offset:512" : "=v"(r01) : "v"(ta));
    asm volatile("ds_read_b64_tr_b16 %0, %1 offset:128" : "=v"(r10) : "v"(ta));
    asm volatile("ds_read_b64_tr_b16 %0, %1 offset:640" : "=v"(r11) : "v"(ta));
    asm volatile("ds_read_b64_tr_b16 %0, %1 offset:256" : "=v"(r20) : "v"(ta));
    asm volatile("ds_read_b64_tr_b16 %0, %1 offset:768" : "=v"(r21) : "v"(ta));
    asm volatile("ds_read_b64_tr_b16 %0, %1 offset:384" : "=v"(r30) : "v"(ta));
    asm volatile("ds_read_b64_tr_b16 %0, %1 offset:896" : "=v"(r31) : "v"(ta));
    asm volatile("s_waitcnt lgkmcnt(0)" ::: "memory");
    __builtin_amdgcn_sched_barrier(0);

    fragU fa;
    fa.q[0] = r00; fa.q[1] = r01;
    acc[0][0] = __builtin_amdgcn_mfma_f32_16x16x32_bf16(fa.v, fb0.v, acc[0][0], 0, 0, 0);
    acc[0][1] = __builtin_amdgcn_mfma_f32_16x16x32_bf16(fa.v, fb1.v, acc[0][1], 0, 0, 0);
    fa.q[0] = r10; fa.q[1] = r11;
    acc[1][0] = __builtin_amdgcn_mfma_f32_16x16x32_bf16(fa.v, fb0.v, acc[1][0], 0, 0, 0);
    acc[1][1] = __builtin_amdgcn_mfma_f32_16x16x32_bf16(fa.v, fb1.v, acc[1][1], 0, 0, 0);
    fa.q[0] = r20; fa.q[1] = r21;
    acc[2][0] = __builtin_amdgcn_mfma_f32_16x16x32_bf16(fa.v, fb0.v, acc[2][0], 0, 0, 0);
    acc[2][1] = __builtin_amdgcn_mfma_f32_16x16x32_bf16(fa.v, fb1.v, acc[2][1], 0, 0, 0);
    fa.q[0] = r30; fa.q[1] = r31;
    acc[3][0] = __builtin_amdgcn_mfma_f32_16x16x32_bf16(fa.v, fb0.v, acc[3][0], 0, 0, 0);
    acc[3][1] = __builtin_amdgcn_mfma_f32_16x16x32_bf16(fa.v, fb1.v, acc[3][1], 0, 0, 0);
    __syncthreads();
  }

  ushort_t* pout = parts + (size_t)kk * 524288 + (size_t)(w * 32 + lane15) * 4096
                 + y * 64 + g * 4;
  #pragma unroll
  for (int q = 0; q < 4; ++q) {
    ushort4 p0, p1;
    p0.x = f2bf(acc[q][0][0]); p0.y = f2bf(acc[q][0][1]);
    p0.z = f2bf(acc[q][0][2]); p0.w = f2bf(acc[q][0][3]);
    p1.x = f2bf(acc[q][1][0]); p1.y = f2bf(acc[q][1][1]);
    p1.z = f2bf(acc[q][1][2]); p1.w = f2bf(acc[q][1][3]);
    *(ushort4*)(pout + q * 16)             = p0;
    *(ushort4*)(pout + 16 * 4096 + q * 16) = p1;
  }
}

// ---------------------------------------------------------------------------
// reduce9: sum 9 bf16 tap-partials (+bias); f32 out and/or bf16 mirror.
// ---------------------------------------------------------------------------
__global__ __launch_bounds__(256) void reduce9_k(
    const ushort_t* __restrict__ parts, float* __restrict__ out,
    ushort_t* __restrict__ outbf, const float* __restrict__ bias) {
  int n0 = (blockIdx.x * 256 + threadIdx.x) * 8;
  int co = blockIdx.y;
  size_t off = (size_t)co * 4096 + n0;
  float s[8] = {0, 0, 0, 0, 0, 0, 0, 0};
  #pragma unroll
  for (int kk = 0; kk < 9; ++kk) {
    uint4 v = *(const uint4*)(parts + (size_t)kk * 524288 + off);
    s[0] += bf2f(v.x & 0xffffu); s[1] += bf2f(v.x >> 16);
    s[2] += bf2f(v.y & 0xffffu); s[3] += bf2f(v.y >> 16);
    s[4] += bf2f(v.z & 0xffffu); s[5] += bf2f(v.z >> 16);
    s[6] += bf2f(v.w & 0xffffu); s[7] += bf2f(v.w >> 16);
  }
  float b = bias ? bias[co] : 0.f;
  #pragma unroll
  for (int i = 0; i < 8; ++i) s[i] += b;
  if (out) {
    f32x4 o0 = {s[0], s[1], s[2], s[3]};
    f32x4 o1 = {s[4], s[5], s[6], s[7]};
    *(f32x4*)(out + off)     = o0;
    *(f32x4*)(out + off + 4) = o1;
  }
  if (outbf) {
    ushort4 b0, b1;
    b0.x = f2bf(s[0]); b0.y = f2bf(s[1]); b0.z = f2bf(s[2]); b0.w = f2bf(s[3]);
    b1.x = f2bf(s[4]); b1.y = f2bf(s[5]); b1.z = f2bf(s[6]); b1.w = f2bf(s[7]);
    *(ushort4*)(outbf + off)     = b0;
    *(ushort4*)(outbf + off + 4) = b1;
  }
}

// ---------------------------------------------------------------------------
// qkv_mfma: 1x1-conv MFMA GEMM. grid (64 pixblk, 6 tiles), block 256.
// ---------------------------------------------------------------------------
__global__ __launch_bounds__(256) void qkv_mfma_k(
    const ushort_t* __restrict__ lidBF, const ushort_t* __restrict__ camBF,
    const ushort_t* __restrict__ Wq,
    ushort_t* __restrict__ lidQK, ushort_t* __restrict__ camQK,
    ushort_t* __restrict__ camV, ushort_t* __restrict__ lidV) {
  __shared__ __align__(16) ushort_t Abuf[2][2048];
  const int y = blockIdx.x, t = blockIdx.y;
  const ushort_t* X = (t >= 2 && t <= 4) ? camBF : lidBF;
  const int tid = threadIdx.x;
  const int w = tid >> 6, l = tid & 63;
  const int lane15 = l & 15, g = l >> 4;
  const int ci_l = w * 8 + (l >> 5) * 4 + ((l & 7) >> 1);
  const int m0   = ((l >> 3) & 3) * 16 + (l & 1) * 8;
  const ushort_t* src = X + (size_t)ci_l * 4096 + y * 64 + m0;
  const ushort_t* wbase = Wq + (size_t)t * 16384 + (w * 32 + lane15) * 128 + g * 8;
  const unsigned tr_base = LDS_U32(&Abuf[0][0]) + (unsigned)(g * 1024 + lane15 * 8);

  f32x4 acc[4][2];
  #pragma unroll
  for (int q = 0; q < 4; ++q) {
    acc[q][0] = (f32x4){0.f, 0.f, 0.f, 0.f};
    acc[q][1] = (f32x4){0.f, 0.f, 0.f, 0.f};
  }

  __builtin_amdgcn_global_load_lds(
      (const __attribute__((address_space(1))) unsigned*)src,
      (__attribute__((address_space(3))) unsigned*)(&Abuf[0][w * 512]), 16, 0, 0);
  __syncthreads();

  for (int s = 0; s < 4; ++s) {
    if (s < 3) {
      const ushort_t* srcn = src + (size_t)(s + 1) * 32 * 4096;
      __builtin_amdgcn_global_load_lds(
          (const __attribute__((address_space(1))) unsigned*)srcn,
          (__attribute__((address_space(3))) unsigned*)(&Abuf[(s + 1) & 1][w * 512]), 16, 0, 0);
    }
    const ushort_t* wb = wbase + s * 32;
    fragU fb0, fb1;
    fb0.u4 = *(const uint4*)(wb);
    fb1.u4 = *(const uint4*)(wb + 16 * 128);

    unsigned ta = tr_base + (unsigned)((s & 1) << 12);
    unsigned long long r00, r01, r10, r11, r20, r21, r30, r31;
    asm volatile("ds_read_b64_tr_b16 %0, %1 offset:0"   : "=v"(r00) : "v"(ta));
    asm volatile("ds_read_b64_tr_b16 %0, %1 offset:512" : "=v"(r01) : "v"(ta));
    asm volatile("ds_read_b64_tr_b16 %0, %1 offset:128" : "=v"(r10) : "v"(ta));
    asm volatile("ds_read_b64_tr_b16 %0, %1 offset:640" : "=v"(r11) : "v"(ta));
    asm volatile("ds_read_b64_tr_b16 %0, %1 offset:256" : "=v"(r20) : "v"(ta));
    asm volatile("ds_read_b64_tr_b16 %0, %1 offset:768" : "=v"(r21) : "v"(ta));
    asm volatile("ds_read_b64_tr_b16 %0, %1 offset:384" : "=v"(r30) : "v"(ta));
    asm volatile("ds_read_b64_tr_b16 %0, %1 offset:896" : "=v"(r31) : "v"(ta));
    asm volatile("s_waitcnt lgkmcnt(0)" ::: "memory");
    __builtin_amdgcn_sched_barrier(0);

    fragU fa;
    fa.q[0] = r00; fa.q[1] = r01;
    acc[0][0] = __builtin_amdgcn_mfma_f32_16x16x32_bf16(fa.v, fb0.v, acc[0][0], 0, 0, 0);
    acc[0][1] = __builtin_amdgcn_mfma_f32_16x16x32_bf16(fa.v, fb1.v, acc[0][1], 0, 0, 0);
    fa.q[0] = r10; fa.q[1] = r11;
    acc[1][0] = __builtin_amdgcn_mfma_f32_16x16x32_bf16(fa.v, fb0.v, acc[1][0], 0, 0, 0);
    acc[1][1] = __builtin_amdgcn_mfma_f32_16x16x32_bf16(fa.v, fb1.v, acc[1][1], 0, 0, 0);
    fa.q[0] = r20; fa.q[1] = r21;
    acc[2][0] = __builtin_amdgcn_mfma_f32_16x16x32_bf16(fa.v, fb0.v, acc[2][0], 0, 0, 0);
    acc[2][1] = __builtin_amdgcn_mfma_f32_16x16x32_bf16(fa.v, fb1.v, acc[2][1], 0, 0, 0);
    fa.q[0] = r30; fa.q[1] = r31;
    acc[3][0] = __builtin_amdgcn_mfma_f32_16x16x32_bf16(fa.v, fb0.v, acc[3][0], 0, 0, 0);
    acc[3][1] = __builtin_amdgcn_mfma_f32_16x16x32_bf16(fa.v, fb1.v, acc[3][1], 0, 0, 0);
    __syncthreads();
  }

  if (t < 4) {
    ushort_t* dst = (t < 2) ? lidQK : camQK;
    const int colbase = (t & 1) * 128 + w * 32 + lane15;
    #pragma unroll
    for (int q = 0; q < 4; ++q)
      #pragma unroll
      for (int tt = 0; tt < 2; ++tt)
        #pragma unroll
        for (int r = 0; r < 4; ++r) {
          int n = y * 64 + q * 16 + g * 4 + r;
          dst[(size_t)n * 256 + colbase + tt * 16] = f2bf(acc[q][tt][r]);
        }
  } else {
    ushort_t* dst = (t == 4) ? camV : lidV;
    ushort_t* pout = dst + (size_t)(w * 32 + lane15) * 4096 + y * 64 + g * 4;
    #pragma unroll
    for (int q = 0; q < 4; ++q) {
      ushort4 p0, p1;
      p0.x = f2bf(acc[q][0][0]); p0.y = f2bf(acc[q][0][1]);
      p0.z = f2bf(acc[q][0][2]); p0.w = f2bf(acc[q][0][3]);
      p1.x = f2bf(acc[q][1][0]); p1.y = f2bf(acc[q][1][1]);
      p1.z = f2bf(acc[q][1][2]); p1.w = f2bf(acc[q][1][3]);
      *(ushort4*)(pout + q * 16)             = p0;
      *(ushort4*)(pout + 16 * 4096 + q * 16) = p1;
    }
  }
}

// ---------------------------------------------------------------------------
// flash attention v10 = static-max 32x32 structure, KEY-SPLIT x4 for
// occupancy (4 blocks/CU = 4 waves/SIMD). Combine is exact-linear (m == 0)
// so splits just sum in proj. grid (32 qblk, 4 h, 8 = attn*4+split),
// block 256 = 4 waves x 32 q-rows; 1024 keys/block, 16 iters.
// ---------------------------------------------------------------------------
__global__ __launch_bounds__(256) void flash_attn_mfma(
    const ushort_t* __restrict__ lidQK, const ushort_t* __restrict__ camQK,
    const ushort_t* __restrict__ camV, const ushort_t* __restrict__ lidV,
    char* __restrict__ ws) {
  const int i0    = blockIdx.x * 128;
  const int h     = blockIdx.y;
  const int z     = blockIdx.z;
  const int attn  = z >> 2;
  const int split = z & 3;
  const int kbase = split * 1024;
  const ushort_t* QK = attn ? camQK : lidQK;

  __shared__ __align__(16) ushort_t Ks[2][64 * 40];   // [k][32d], 80B rows
  __shared__ __align__(16) ushort_t Vt[2][64 * 72];   // [tensor*32+d][64k], 144B rows

  const int tid = threadIdx.x;
  const int w = tid >> 6, l = tid & 63;
  const int q31 = l & 31, hi = l >> 5;
  const int q0w = i0 + w * 32;

  const int srow = tid >> 2, sc = tid & 3;
  const ushort_t* Kg = QK + (size_t)(kbase + srow) * 256 + 128 + h * 32 + sc * 8;
  const ushort_t* Vg = ((srow >> 5) ? lidV : camV)
                     + (size_t)(h * 32 + (srow & 31)) * N_PIX + kbase;

  fragU qf0, qf1;
  qf0.u4 = *(const uint4*)(QK + (size_t)(q0w + q31) * 256 + h * 32 + hi * 8);
  qf1.u4 = *(const uint4*)(QK + (size_t)(q0w + q31) * 256 + h * 32 + 16 + hi * 8);

  { // prologue staging
    uint4 k4 = *(const uint4*)Kg;
    uint4 va = *(const uint4*)(Vg + sc * 8);
    uint4 vb = *(const uint4*)(Vg + (sc + 4) * 8);
    *(uint4*)(&Ks[0][srow * 40 + sc * 8]) = k4;
    *(uint4*)(&Vt[0][srow * 72 + sc * 8]) = va;
    *(uint4*)(&Vt[0][srow * 72 + (sc + 4) * 8]) = vb;
  }
  __syncthreads();

  fragU ones;
  #pragma unroll
  for (int j = 0; j < 8; ++j) ones.us[j] = 0x3F80;   // bf16 1.0

  f32x16 Oc = (f32x16)0.f, Ol = (f32x16)0.f, lacc = (f32x16)0.f;
  const f32x16 z16 = (f32x16)0.f;                     // loop-invariant C=0

  for (int it = 0; it < 16; ++it) {
    const int cur = it & 1, nxt = cur ^ 1;
    const bool more = (it + 1) < 16;
    uint4 kn, van, vbn;
    if (more) {
      kn  = *(const uint4*)(Kg + (size_t)(it + 1) * 16384);
      van = *(const uint4*)(Vg + (it + 1) * 64 + sc * 8);
      vbn = *(const uint4*)(Vg + (it + 1) * 64 + (sc + 4) * 8);
    }

    // ---- QK: S^T (2 k-tiles x 2 d-slices) ----
    const ushort_t* kb = &Ks[cur][0];
    fragU k00, k01, k10, k11;
    k00.u4 = *(const uint4*)(kb + q31 * 40 + hi * 8);
    k01.u4 = *(const uint4*)(kb + q31 * 40 + 16 + hi * 8);
    k10.u4 = *(const uint4*)(kb + (32 + q31) * 40 + hi * 8);
    k11.u4 = *(const uint4*)(kb + (32 + q31) * 40 + 16 + hi * 8);
    f32x16 S0, S1;
    __builtin_amdgcn_s_setprio(1);
    S0 = __builtin_amdgcn_mfma_f32_32x32x16_bf16(k00.v, qf0.v, z16, 0, 0, 0);
    S0 = __builtin_amdgcn_mfma_f32_32x32x16_bf16(k01.v, qf1.v, S0, 0, 0, 0);
    S1 = __builtin_amdgcn_mfma_f32_32x32x16_bf16(k10.v, qf0.v, z16, 0, 0, 0);
    S1 = __builtin_amdgcn_mfma_f32_32x32x16_bf16(k11.v, qf1.v, S1, 0, 0, 0);
    __builtin_amdgcn_s_setprio(0);

    // ---- static-max softmax: P = exp2(S) directly ----
    #pragma unroll
    for (int j = 0; j < 16; ++j) S0[j] = __builtin_amdgcn_exp2f(S0[j]);
    #pragma unroll
    for (int j = 0; j < 16; ++j) S1[j] = __builtin_amdgcn_exp2f(S1[j]);

    // ---- P -> A-frags: cvt_pk pairs + permlane32_swap ----
    fragU pa0, pa1, pa2, pa3;
    {
      unsigned a0, a1, b0, b1;
      asm("v_cvt_pk_bf16_f32 %0, %1, %2" : "=v"(a0) : "v"(S0[0]),  "v"(S0[1]));
      asm("v_cvt_pk_bf16_f32 %0, %1, %2" : "=v"(a1) : "v"(S0[2]),  "v"(S0[3]));
      asm("v_cvt_pk_bf16_f32 %0, %1, %2" : "=v"(b0) : "v"(S0[4]),  "v"(S0[5]));
      asm("v_cvt_pk_bf16_f32 %0, %1, %2" : "=v"(b1) : "v"(S0[6]),  "v"(S0[7]));
      uint2v r0 = __builtin_amdgcn_permlane32_swap(a0, b0, false, false);
      uint2v r1 = __builtin_amdgcn_permlane32_swap(a1, b1, false, false);
      pa0.u[0] = r0[0]; pa0.u[1] = r1[0]; pa0.u[2] = r0[1]; pa0.u[3] = r1[1];
      asm("v_cvt_pk_bf16_f32 %0, %1, %2" : "=v"(a0) : "v"(S0[8]),  "v"(S0[9]));
      asm("v_cvt_pk_bf16_f32 %0, %1, %2" : "=v"(a1) : "v"(S0[10]), "v"(S0[11]));
      asm("v_cvt_pk_bf16_f32 %0, %1, %2" : "=v"(b0) : "v"(S0[12]), "v"(S0[13]));
      asm("v_cvt_pk_bf16_f32 %0, %1, %2" : "=v"(b1) : "v"(S0[14]), "v"(S0[15]));
      r0 = __builtin_amdgcn_permlane32_swap(a0, b0, false, false);
      r1 = __builtin_amdgcn_permlane32_swap(a1, b1, false, false);
      pa1.u[0] = r0[0]; pa1.u[1] = r1[0]; pa1.u[2] = r0[1]; pa1.u[3] = r1[1];
      asm("v_cvt_pk_bf16_f32 %0, %1, %2" : "=v"(a0) : "v"(S1[0]),  "v"(S1[1]));
      asm("v_cvt_pk_bf16_f32 %0, %1, %2" : "=v"(a1) : "v"(S1[2]),  "v"(S1[3]));
      asm("v_cvt_pk_bf16_f32 %0, %1, %2" : "=v"(b0) : "v"(S1[4]),  "v"(S1[5]));
      asm("v_cvt_pk_bf16_f32 %0, %1, %2" : "=v"(b1) : "v"(S1[6]),  "v"(S1[7]));
      r0 = __builtin_amdgcn_permlane32_swap(a0, b0, false, false);
      r1 = __builtin_amdgcn_permlane32_swap(a1, b1, false, false);
      pa2.u[0] = r0[0]; pa2.u[1] = r1[0]; pa2.u[2] = r0[1]; pa2.u[3] = r1[1];
      asm("v_cvt_pk_bf16_f32 %0, %1, %2" : "=v"(a0) : "v"(S1[8]),  "v"(S1[9]));
      asm("v_cvt_pk_bf16_f32 %0, %1, %2" : "=v"(a1) : "v"(S1[10]), "v"(S1[11]));
      asm("v_cvt_pk_bf16_f32 %0, %1, %2" : "=v"(b0) : "v"(S1[12]), "v"(S1[13]));
      asm("v_cvt_pk_bf16_f32 %0, %1, %2" : "=v"(b1) : "v"(S1[14]), "v"(S1[15]));
      r0 = __builtin_amdgcn_permlane32_swap(a0, b0, false, false);
      r1 = __builtin_amdgcn_permlane32_swap(a1, b1, false, false);
      pa3.u[0] = r0[0]; pa3.u[1] = r1[0]; pa3.u[2] = r0[1]; pa3.u[3] = r1[1];
    }

    // ---- PV: 4 k-slices x 2 tensors + row-sum via ones-MFMA ----
    const ushort_t* vb = &Vt[cur][0];
    __builtin_amdgcn_s_setprio(1);
    {
      fragU vc, vl;
      vc.u4 = *(const uint4*)(vb + q31 * 72 + hi * 8);
      vl.u4 = *(const uint4*)(vb + (32 + q31) * 72 + hi * 8);
      Oc = __builtin_amdgcn_mfma_f32_32x32x16_bf16(pa0.v, vc.v, Oc, 0, 0, 0);
      Ol = __builtin_amdgcn_mfma_f32_32x32x16_bf16(pa0.v, vl.v, Ol, 0, 0, 0);
      lacc = __builtin_amdgcn_mfma_f32_32x32x16_bf16(pa0.v, ones.v, lacc, 0, 0, 0);
      vc.u4 = *(const uint4*)(vb + q31 * 72 + 16 + hi * 8);
      vl.u4 = *(const uint4*)(vb + (32 + q31) * 72 + 16 + hi * 8);
      Oc = __builtin_amdgcn_mfma_f32_32x32x16_bf16(pa1.v, vc.v, Oc, 0, 0, 0);
      Ol = __builtin_amdgcn_mfma_f32_32x32x16_bf16(pa1.v, vl.v, Ol, 0, 0, 0);
      lacc = __builtin_amdgcn_mfma_f32_32x32x16_bf16(pa1.v, ones.v, lacc, 0, 0, 0);
      vc.u4 = *(const uint4*)(vb + q31 * 72 + 32 + hi * 8);
      vl.u4 = *(const uint4*)(vb + (32 + q31) * 72 + 32 + hi * 8);
      Oc = __builtin_amdgcn_mfma_f32_32x32x16_bf16(pa2.v, vc.v, Oc, 0, 0, 0);
      Ol = __builtin_amdgcn_mfma_f32_32x32x16_bf16(pa2.v, vl.v, Ol, 0, 0, 0);
      lacc = __builtin_amdgcn_mfma_f32_32x32x16_bf16(pa2.v, ones.v, lacc, 0, 0, 0);
      vc.u4 = *(const uint4*)(vb + q31 * 72 + 48 + hi * 8);
      vl.u4 = *(const uint4*)(vb + (32 + q31) * 72 + 48 + hi * 8);
      Oc = __builtin_amdgcn_mfma_f32_32x32x16_bf16(pa3.v, vc.v, Oc, 0, 0, 0);
      Ol = __builtin_amdgcn_mfma_f32_32x32x16_bf16(pa3.v, vl.v, Ol, 0, 0, 0);
      lacc = __builtin_amdgcn_mfma_f32_32x32x16_bf16(pa3.v, ones.v, lacc, 0, 0, 0);
    }
    __builtin_amdgcn_s_setprio(0);

    if (more) {
      *(uint4*)(&Ks[nxt][srow * 40 + sc * 8]) = kn;
      *(uint4*)(&Vt[nxt][srow * 72 + sc * 8]) = van;
      *(uint4*)(&Vt[nxt][srow * 72 + (sc + 4) * 8]) = vbn;
    }
    __syncthreads();
  }

  // epilogue: unnormalized bf16 partials; rows q = crow(reg,hi).
  const int si = (attn * 4 + split) * 2;
  ushort_t* OPc = (ushort_t*)(ws + op_off(si + 0));
  ushort_t* OPl = (ushort_t*)(ws + op_off(si + 1));
  float2* ML = (float2*)(ws + ML_OFF);
  const int d = h * 32 + q31;
  #pragma unroll
  for (int reg = 0; reg < 16; ++reg) {
    int n = q0w + (reg & 3) + 8 * (reg >> 2) + 4 * hi;
    OPc[(size_t)n * 128 + d] = f2bf(Oc[reg]);
    OPl[(size_t)n * 128 + d] = f2bf(Ol[reg]);
  }
  if (q31 == 0) {
    #pragma unroll
    for (int reg = 0; reg < 16; ++reg) {
      int n = q0w + (reg & 3) + 8 * (reg >> 2) + 4 * hi;
      float2 v; v.x = 0.f; v.y = lacc[reg];
      ML[(size_t)(attn * 4 + split) * 4096 + n] = v;
    }
  }
}

// ---------------------------------------------------------------------------
// proj_mfma: 4-way key-split combine (exact-linear, static max) + projection
// GEMM + residual + bias -> padded bf16 fuser-conv inputs.
// grid (64 nblk, 4 ot), block 256. Residuals from bf16 mirrors.
// ---------------------------------------------------------------------------
__global__ __launch_bounds__(256) void proj_mfma_k(
    const char* __restrict__ ws,
    const ushort_t* __restrict__ Wlid, const ushort_t* __restrict__ Wcam,
    const ushort_t* __restrict__ camBF, const ushort_t* __restrict__ lidBF,
    const float* __restrict__ cam_proj_b, const float* __restrict__ lid_proj_b,
    ushort_t* __restrict__ fm, ushort_t* __restrict__ fh) {
  const int n0 = blockIdx.x * 64;
  const int ot = blockIdx.y;
  const int attn = (ot == 0 || ot == 2) ? 1 : 0;
  const int vt = ot >> 1;
  const int tid = threadIdx.x;
  const int w = tid >> 6, l = tid & 63;
  const int m = l & 15, g = l >> 4;

  const float2* ML = (const float2*)(ws + ML_OFF);
  const int arow = n0 + w * 16 + m;

  float lsum = 0.f;
  #pragma unroll
  for (int s = 0; s < 4; ++s)
    lsum += ML[(size_t)(attn * 4 + s) * 4096 + arow].y;
  float inv = 1.0f / lsum;

  const ushort_t* O0 = (const ushort_t*)(ws + op_off((attn * 4 + 0) * 2 + vt));
  const ushort_t* O1 = (const ushort_t*)(ws + op_off((attn * 4 + 1) * 2 + vt));
  const ushort_t* O2 = (const ushort_t*)(ws + op_off((attn * 4 + 2) * 2 + vt));
  const ushort_t* O3 = (const ushort_t*)(ws + op_off((attn * 4 + 3) * 2 + vt));

  fragU afr[4];
  #pragma unroll
  for (int s = 0; s < 4; ++s) {
    fragU x0, x1, x2, x3;
    x0.u4 = *(const uint4*)(O0 + (size_t)arow * 128 + s * 32 + g * 8);
    x1.u4 = *(const uint4*)(O1 + (size_t)arow * 128 + s * 32 + g * 8);
    x2.u4 = *(const uint4*)(O2 + (size_t)arow * 128 + s * 32 + g * 8);
    x3.u4 = *(const uint4*)(O3 + (size_t)arow * 128 + s * 32 + g * 8);
    #pragma unroll
    for (int j = 0; j < 8; ++j)
      afr[s].us[j] = f2bf(inv * (bf2f(x0.us[j]) + bf2f(x1.us[j])
                               + bf2f(x2.us[j]) + bf2f(x3.us[j])));
  }

  const ushort_t* W = (ot == 1) ? Wcam : Wlid;
  f32x4 acc[8];
  #pragma unroll
  for (int t = 0; t < 8; ++t) acc[t] = (f32x4){0.f, 0.f, 0.f, 0.f};
  #pragma unroll
  for (int s = 0; s < 4; ++s) {
    #pragma unroll
    for (int t = 0; t < 8; ++t) {
      fragU bfr;
      bfr.u4 = *(const uint4*)(W + (size_t)(t * 16 + m) * 128 + s * 32 + g * 8);
      acc[t] = __builtin_amdgcn_mfma_f32_16x16x32_bf16(afr[s].v, bfr.v, acc[t], 0, 0, 0);
    }
  }

  const float* bias = (ot == 1) ? cam_proj_b : lid_proj_b;
  const ushort_t* resBF = (ot < 2) ? camBF : lidBF;
  const int doff = ot * 126;
  #pragma unroll
  for (int t = 0; t < 8; ++t) {
    int co = t * 16 + m;
    if (co < 126) {
      float b = bias[co];
      #pragma unroll
      for (int r = 0; r < 4; ++r) {
        int n = n0 + w * 16 + g * 4 + r;
        float res = bf2f(resBF[(size_t)co * N_PIX + n]);
        float v = acc[t][r] + res + b;
        unsigned short bf = f2bf(v);
        int y = n >> 6, x = n & 63;
        fm[(doff + co) * 4224 + (y + 1) * 64 + x]      = bf;
        fh[(doff + co) * 4356 + (y + 1) * 66 + x + 1]  = bf;
      }
    }
  }
}

// ---------------------------------------------------------------------------
extern "C" void kernel_launch(void* const* d_in, const int* in_sizes, int n_in,
                              void* d_out, int out_size, void* d_ws, size_t ws_size,
                              hipStream_t stream) {
  (void)in_sizes; (void)n_in; (void)out_size; (void)ws_size;
  const float* lidar_bev  = (const float*)d_in[0];
  const float* cam_bev    = (const float*)d_in[1];
  const float* cam_enc_w  = (const float*)d_in[2];
  const float* cam_enc_b  = (const float*)d_in[3];
  const float* cam_v_w    = (const float*)d_in[4];
  const float* cam_qk_w   = (const float*)d_in[5];
  const float* cam_proj_w = (const float*)d_in[6];
  const float* cam_proj_b = (const float*)d_in[7];
  const float* lid_v_w    = (const float*)d_in[8];
  const float* lid_qk_w   = (const float*)d_in[9];
  const float* lid_proj_w = (const float*)d_in[10];
  const float* lid_proj_b = (const float*)d_in[11];
  const float* fuser_w    = (const float*)d_in[12];
  float* out = (float*)d_out;

  char* p = (char*)d_ws;
  // conv phases: arena [0, 9437184) = 9 tap-partial slices.
  // attention phase: OP slices 0-8 in arena, slices 9-15 in the fusBF region
  // (fusBF is zeroed AFTER flash, before proj); ML at ex-cam_enc offset.
  ushort_t* arena = (ushort_t*)p;
  ushort_t* lidQK = (ushort_t*)(p + 9437184);      // [4096][256] bf16
  ushort_t* camQK = (ushort_t*)(p + 11534336);
  ushort_t* camV  = (ushort_t*)(p + 13631488);     // [128][4096] bf16
  ushort_t* lidV  = (ushort_t*)(p + 14680064);
  // [15728640, +262144): ML during attention
  ushort_t* Wp_c    = (ushort_t*)(p + 17793024);   // [9][128][96]
  ushort_t* Wp_f    = (ushort_t*)(p + 18014208);   // [9][128][512]
  ushort_t* Wp_lid  = (ushort_t*)(p + 19193856);   // [128][128]
  ushort_t* Wp_cam  = (ushort_t*)(p + 19226624);   // [128][128]
  ushort_t* Wq      = (ushort_t*)(p + 19259392);   // [6][128][128]
  ushort_t* lidBF   = (ushort_t*)(p + 19456000);   // [128][4096] (126 used)
  ushort_t* camBF   = (ushort_t*)(p + 20504576);   // [128][4096] bf16 cam_enc
  ushort_t* camBF_m = (ushort_t*)(p + 21553152);   // [96][66][64]
  ushort_t* camBF_h = (ushort_t*)(p + 22364160);   // [96][66][66]
  ushort_t* fusBF_m = (ushort_t*)(p + 23200512);   // [512][66][64]; OP 9-15 during attn
  ushort_t* fusBF_h = (ushort_t*)(p + 27525888);   // [512][66][66] (end 31986432)

  // zero cam halo buffers only (1,647,360 B); fusBF zeroed after flash.
  zero_span_k<<<403, 256, 0, stream>>>((uint4*)(p + 21553152), 102960);
  prep_k<<<6544, 256, 0, stream>>>(cam_enc_w, fuser_w, lid_proj_w, cam_proj_w,
                                   lid_qk_w, cam_qk_w, cam_v_w, lid_v_w,
                                   cam_bev, lidar_bev,
                                   Wp_c, Wp_f, Wp_lid, Wp_cam, Wq,
                                   camBF_m, camBF_h, lidBF);

  conv_mfma_k<<<dim3(64, 9), 256, 0, stream>>>(camBF_m, camBF_h, Wp_c, arena, 96, 3);
  reduce9_k<<<dim3(2, 126), 256, 0, stream>>>(arena, nullptr, camBF, cam_enc_b);

  qkv_mfma_k<<<dim3(64, 6), 256, 0, stream>>>(lidBF, camBF, Wq, lidQK, camQK, camV, lidV);
  flash_attn_mfma<<<dim3(32, 4, 8), 256, 0, stream>>>(lidQK, camQK, camV, lidV, p);
  // zero the fuser-conv input buffers (8,785,920 B) now that OP is consumed...
  // (must precede proj, which writes the interiors)
  zero_span_k<<<2145, 256, 0, stream>>>((uint4*)(p + 23200512), 549120);
  proj_mfma_k<<<dim3(64, 4), 256, 0, stream>>>(p, Wp_lid, Wp_cam, camBF, lidBF,
                                               cam_proj_b, lid_proj_b, fusBF_m, fusBF_h);

  conv_mfma_k<<<dim3(64, 9), 256, 0, stream>>>(fusBF_m, fusBF_h, Wp_f, arena, 512, 16);
  reduce9_k<<<dim3(2, 126), 256, 0, stream>>>(arena, out, nullptr, nullptr);
}

// Round 12
// 113.989 us; speedup vs baseline: 1.0241x; 1.0241x over previous
//
#include <hip/hip_runtime.h>
#include <hip/hip_bf16.h>

typedef unsigned short ushort_t;
using f32x4  = __attribute__((ext_vector_type(4))) float;
using f32x16 = __attribute__((ext_vector_type(16))) float;
using bf16x8 = __attribute__((ext_vector_type(8))) short;
typedef unsigned uint2v __attribute__((ext_vector_type(2)));

#define N_PIX 4096

static __device__ __forceinline__ unsigned short f2bf(float f) {
  unsigned int u = __builtin_bit_cast(unsigned int, f);
  u += 0x7FFFu + ((u >> 16) & 1u);   // round-to-nearest-even
  return (unsigned short)(u >> 16);
}
static __device__ __forceinline__ float bf2f(unsigned int us) {
  return __builtin_bit_cast(float, us << 16);
}

typedef union {
  uint4 u4;
  unsigned u[4];
  unsigned long long q[2];
  bf16x8 v;
  unsigned short us[8];
} fragU;

#define LDS_U32(p) ((unsigned)(uintptr_t)((__attribute__((address_space(3))) void*)(p)))

// ---------------------------------------------------------------------------
__global__ __launch_bounds__(256) void zero_span_k(uint4* __restrict__ p, int n16) {
  int i = blockIdx.x * 256 + threadIdx.x;
  if (i < n16) p[i] = (uint4){0u, 0u, 0u, 0u};
}

// ---------------------------------------------------------------------------
// prep_k: fused weight pack + input convert.
// ---------------------------------------------------------------------------
__global__ __launch_bounds__(256) void prep_k(
    const float* __restrict__ cam_enc_w, const float* __restrict__ fuser_w,
    const float* __restrict__ lid_proj_w, const float* __restrict__ cam_proj_w,
    const float* __restrict__ lid_qk_w, const float* __restrict__ cam_qk_w,
    const float* __restrict__ cam_v_w, const float* __restrict__ lid_v_w,
    const float* __restrict__ cam_bev, const float* __restrict__ lidar_bev,
    ushort_t* __restrict__ Wp_c, ushort_t* __restrict__ Wp_f,
    ushort_t* __restrict__ Wp_lid, ushort_t* __restrict__ Wp_cam,
    ushort_t* __restrict__ Wq,
    ushort_t* __restrict__ cm, ushort_t* __restrict__ ch_,
    ushort_t* __restrict__ lidBF) {
  const float QSCALE = 0.08908708063747479f * 1.4426950408889634f;
  int idx = blockIdx.x * 256 + threadIdx.x;
  if (idx < 110592) {                     // 9*128*96
    int kk = idx / 12288, r = idx % 12288;
    int co = r / 96, ci = r % 96;
    float v = (co < 126 && ci < 80) ? cam_enc_w[(co * 80 + ci) * 9 + kk] : 0.f;
    Wp_c[idx] = f2bf(v);
  } else if (idx < 700416) {              // 9*128*512
    int j = idx - 110592;
    int kk = j / 65536, r = j % 65536;
    int co = r / 512, ci = r % 512;
    float v = (co < 126 && ci < 504) ? fuser_w[(co * 504 + ci) * 9 + kk] : 0.f;
    Wp_f[j] = f2bf(v);
  } else if (idx < 716800) {              // 128*128
    int j = idx - 700416;
    int co = j >> 7, k = j & 127;
    Wp_lid[j] = f2bf(co < 126 ? lid_proj_w[co * 128 + k] : 0.f);
  } else if (idx < 733184) {
    int j = idx - 716800;
    int co = j >> 7, k = j & 127;
    Wp_cam[j] = f2bf(co < 126 ? cam_proj_w[co * 128 + k] : 0.f);
  } else if (idx < 831488) {              // 6*128*128
    int j = idx - 733184;
    int t = j >> 14, r = j & 16383;
    int row = r >> 7, ci = r & 127;
    float v = 0.f;
    if (ci < 126) {
      if (t == 0)      v = lid_qk_w[row * 126 + ci] * QSCALE;
      else if (t == 1) v = lid_qk_w[(128 + row) * 126 + ci];
      else if (t == 2) v = cam_qk_w[row * 126 + ci] * QSCALE;
      else if (t == 3) v = cam_qk_w[(128 + row) * 126 + ci];
      else if (t == 4) v = cam_v_w[row * 126 + ci];
      else             v = lid_v_w[row * 126 + ci];
    }
    Wq[j] = f2bf(v);
  } else {
    int k = idx - 831488;
    if (k < 327680) {                     // 80*4096 cam
      int ch = k >> 12, n = k & 4095;
      int y = n >> 6, x = n & 63;
      unsigned short b = f2bf(cam_bev[k]);
      cm[ch * 4224 + (y + 1) * 64 + x] = b;
      ch_[ch * 4356 + (y + 1) * 66 + (x + 1)] = b;
    } else {
      int j = k - 327680;                 // 126*4096 lidar
      if (j < 516096) lidBF[j] = f2bf(lidar_bev[j]);
    }
  }
}

// ---------------------------------------------------------------------------
// conv_mfma: implicit-GEMM 3x3 conv, one (ky,kx) tap per blockIdx.y. bf16 parts.
// ---------------------------------------------------------------------------
__global__ __launch_bounds__(256) void conv_mfma_k(
    const ushort_t* __restrict__ Amain,   // [CIp][66][64]
    const ushort_t* __restrict__ Ahalo,   // [CIp][66][66]
    const ushort_t* __restrict__ Wp,      // [9][128][CIp]
    ushort_t* __restrict__ parts,
    int CIp, int ksteps) {
  __shared__ __align__(16) ushort_t Abuf[2][2048];
  const int y   = blockIdx.x;
  const int kk  = blockIdx.y;
  const int ky  = kk / 3, kx = kk - ky * 3;
  const int tid = threadIdx.x;
  const int w   = tid >> 6, l = tid & 63;
  const int lane15 = l & 15, g = l >> 4;
  const int yy1 = y + ky;

  const int ci_l = w * 8 + (l >> 5) * 4 + ((l & 7) >> 1);
  const int m0   = ((l >> 3) & 3) * 16 + (l & 1) * 8;
  const ushort_t* src;
  size_t plane;
  if (kx == 1) { plane = 66 * 64; src = Amain + (size_t)ci_l * plane + yy1 * 64 + m0; }
  else         { plane = 66 * 66; src = Ahalo + (size_t)ci_l * plane + yy1 * 66 + m0 + kx; }

  const ushort_t* wbase = Wp + ((size_t)kk * 128 + w * 32 + lane15) * CIp + g * 8;
  const unsigned tr_base = LDS_U32(&Abuf[0][0]) + (unsigned)(g * 1024 + lane15 * 8);

  f32x4 acc[4][2];
  #pragma unroll
  for (int q = 0; q < 4; ++q) {
    acc[q][0] = (f32x4){0.f, 0.f, 0.f, 0.f};
    acc[q][1] = (f32x4){0.f, 0.f, 0.f, 0.f};
  }

  __builtin_amdgcn_global_load_lds(
      (const __attribute__((address_space(1))) unsigned*)src,
      (__attribute__((address_space(3))) unsigned*)(&Abuf[0][w * 512]), 16, 0, 0);
  __syncthreads();

  for (int s = 0; s < ksteps; ++s) {
    if (s + 1 < ksteps) {
      const ushort_t* srcn = src + (size_t)(s + 1) * 32 * plane;
      __builtin_amdgcn_global_load_lds(
          (const __attribute__((address_space(1))) unsigned*)srcn,
          (__attribute__((address_space(3))) unsigned*)(&Abuf[(s + 1) & 1][w * 512]), 16, 0, 0);
    }
    const ushort_t* wb = wbase + s * 32;
    fragU fb0, fb1;
    fb0.u4 = *(const uint4*)(wb);
    fb1.u4 = *(const uint4*)(wb + 16 * CIp);

    unsigned ta = tr_base + (unsigned)((s & 1) << 12);
    unsigned long long r00, r01, r10, r11, r20, r21, r30, r31;
    asm volatile("ds_read_b64_tr_b16 %0, %1 offset:0"   : "=v"(r00) : "v"(ta));
    asm volatile("ds_read_b64_tr_b16 %0, %1 offset:512" : "=v"(r01) : "v"(ta));
    asm volatile("ds_read_b64_tr_b16 %0, %1 offset:128" : "=v"(r10) : "v"(ta));
    asm volatile("ds_read_b64_tr_b16 %0, %1 offset:640" : "=v"(r11) : "v"(ta));
    asm volatile("ds_read_b64_tr_b16 %0, %1 offset:256" : "=v"(r20) : "v"(ta));
    asm volatile("ds_read_b64_tr_b16 %0, %1 offset:768" : "=v"(r21) : "v"(ta));
    asm volatile("ds_read_b64_tr_b16 %0, %1 offset:384" : "=v"(r30) : "v"(ta));
    asm volatile("ds_read_b64_tr_b16 %0, %1 offset:896" : "=v"(r31) : "v"(ta));
    asm volatile("s_waitcnt lgkmcnt(0)" ::: "memory");
    __builtin_amdgcn_sched_barrier(0);

    fragU fa;
    fa.q[0] = r00; fa.q[1] = r01;
    acc[0][0] = __builtin_amdgcn_mfma_f32_16x16x32_bf16(fa.v, fb0.v, acc[0][0], 0, 0, 0);
    acc[0][1] = __builtin_amdgcn_mfma_f32_16x16x32_bf16(fa.v, fb1.v, acc[0][1], 0, 0, 0);
    fa.q[0] = r10; fa.q[1] = r11;
    acc[1][0] = __builtin_amdgcn_mfma_f32_16x16x32_bf16(fa.v, fb0.v, acc[1][0], 0, 0, 0);
    acc[1][1] = __builtin_amdgcn_mfma_f32_16x16x32_bf16(fa.v, fb1.v, acc[1][1], 0, 0, 0);
    fa.q[0] = r20; fa.q[1] = r21;
    acc[2][0] = __builtin_amdgcn_mfma_f32_16x16x32_bf16(fa.v, fb0.v, acc[2][0], 0, 0, 0);
    acc[2][1] = __builtin_amdgcn_mfma_f32_16x16x32_bf16(fa.v, fb1.v, acc[2][1], 0, 0, 0);
    fa.q[0] = r30; fa.q[1] = r31;
    acc[3][0] = __builtin_amdgcn_mfma_f32_16x16x32_bf16(fa.v, fb0.v, acc[3][0], 0, 0, 0);
    acc[3][1] = __builtin_amdgcn_mfma_f32_16x16x32_bf16(fa.v, fb1.v, acc[3][1], 0, 0, 0);
    __syncthreads();
  }

  ushort_t* pout = parts + (size_t)kk * 524288 + (size_t)(w * 32 + lane15) * 4096
                 + y * 64 + g * 4;
  #pragma unroll
  for (int q = 0; q < 4; ++q) {
    ushort4 p0, p1;
    p0.x = f2bf(acc[q][0][0]); p0.y = f2bf(acc[q][0][1]);
    p0.z = f2bf(acc[q][0][2]); p0.w = f2bf(acc[q][0][3]);
    p1.x = f2bf(acc[q][1][0]); p1.y = f2bf(acc[q][1][1]);
    p1.z = f2bf(acc[q][1][2]); p1.w = f2bf(acc[q][1][3]);
    *(ushort4*)(pout + q * 16)             = p0;
    *(ushort4*)(pout + 16 * 4096 + q * 16) = p1;
  }
}

// ---------------------------------------------------------------------------
// reduce9: sum 9 bf16 tap-partials (+bias); f32 out and/or bf16 mirror.
// ---------------------------------------------------------------------------
__global__ __launch_bounds__(256) void reduce9_k(
    const ushort_t* __restrict__ parts, float* __restrict__ out,
    ushort_t* __restrict__ outbf, const float* __restrict__ bias) {
  int n0 = (blockIdx.x * 256 + threadIdx.x) * 8;
  int co = blockIdx.y;
  size_t off = (size_t)co * 4096 + n0;
  float s[8] = {0, 0, 0, 0, 0, 0, 0, 0};
  #pragma unroll
  for (int kk = 0; kk < 9; ++kk) {
    uint4 v = *(const uint4*)(parts + (size_t)kk * 524288 + off);
    s[0] += bf2f(v.x & 0xffffu); s[1] += bf2f(v.x >> 16);
    s[2] += bf2f(v.y & 0xffffu); s[3] += bf2f(v.y >> 16);
    s[4] += bf2f(v.z & 0xffffu); s[5] += bf2f(v.z >> 16);
    s[6] += bf2f(v.w & 0xffffu); s[7] += bf2f(v.w >> 16);
  }
  float b = bias ? bias[co] : 0.f;
  #pragma unroll
  for (int i = 0; i < 8; ++i) s[i] += b;
  if (out) {
    f32x4 o0 = {s[0], s[1], s[2], s[3]};
    f32x4 o1 = {s[4], s[5], s[6], s[7]};
    *(f32x4*)(out + off)     = o0;
    *(f32x4*)(out + off + 4) = o1;
  }
  if (outbf) {
    ushort4 b0, b1;
    b0.x = f2bf(s[0]); b0.y = f2bf(s[1]); b0.z = f2bf(s[2]); b0.w = f2bf(s[3]);
    b1.x = f2bf(s[4]); b1.y = f2bf(s[5]); b1.z = f2bf(s[6]); b1.w = f2bf(s[7]);
    *(ushort4*)(outbf + off)     = b0;
    *(ushort4*)(outbf + off + 4) = b1;
  }
}

// ---------------------------------------------------------------------------
// qkv_mfma: 1x1-conv MFMA GEMM. grid (64 pixblk, 6 tiles), block 256.
// ---------------------------------------------------------------------------
__global__ __launch_bounds__(256) void qkv_mfma_k(
    const ushort_t* __restrict__ lidBF, const ushort_t* __restrict__ camBF,
    const ushort_t* __restrict__ Wq,
    ushort_t* __restrict__ lidQK, ushort_t* __restrict__ camQK,
    ushort_t* __restrict__ camV, ushort_t* __restrict__ lidV) {
  __shared__ __align__(16) ushort_t Abuf[2][2048];
  const int y = blockIdx.x, t = blockIdx.y;
  const ushort_t* X = (t >= 2 && t <= 4) ? camBF : lidBF;
  const int tid = threadIdx.x;
  const int w = tid >> 6, l = tid & 63;
  const int lane15 = l & 15, g = l >> 4;
  const int ci_l = w * 8 + (l >> 5) * 4 + ((l & 7) >> 1);
  const int m0   = ((l >> 3) & 3) * 16 + (l & 1) * 8;
  const ushort_t* src = X + (size_t)ci_l * 4096 + y * 64 + m0;
  const ushort_t* wbase = Wq + (size_t)t * 16384 + (w * 32 + lane15) * 128 + g * 8;
  const unsigned tr_base = LDS_U32(&Abuf[0][0]) + (unsigned)(g * 1024 + lane15 * 8);

  f32x4 acc[4][2];
  #pragma unroll
  for (int q = 0; q < 4; ++q) {
    acc[q][0] = (f32x4){0.f, 0.f, 0.f, 0.f};
    acc[q][1] = (f32x4){0.f, 0.f, 0.f, 0.f};
  }

  __builtin_amdgcn_global_load_lds(
      (const __attribute__((address_space(1))) unsigned*)src,
      (__attribute__((address_space(3))) unsigned*)(&Abuf[0][w * 512]), 16, 0, 0);
  __syncthreads();

  for (int s = 0; s < 4; ++s) {
    if (s < 3) {
      const ushort_t* srcn = src + (size_t)(s + 1) * 32 * 4096;
      __builtin_amdgcn_global_load_lds(
          (const __attribute__((address_space(1))) unsigned*)srcn,
          (__attribute__((address_space(3))) unsigned*)(&Abuf[(s + 1) & 1][w * 512]), 16, 0, 0);
    }
    const ushort_t* wb = wbase + s * 32;
    fragU fb0, fb1;
    fb0.u4 = *(const uint4*)(wb);
    fb1.u4 = *(const uint4*)(wb + 16 * 128);

    unsigned ta = tr_base + (unsigned)((s & 1) << 12);
    unsigned long long r00, r01, r10, r11, r20, r21, r30, r31;
    asm volatile("ds_read_b64_tr_b16 %0, %1 offset:0"   : "=v"(r00) : "v"(ta));
    asm volatile("ds_read_b64_tr_b16 %0, %1 offset:512" : "=v"(r01) : "v"(ta));
    asm volatile("ds_read_b64_tr_b16 %0, %1 offset:128" : "=v"(r10) : "v"(ta));
    asm volatile("ds_read_b64_tr_b16 %0, %1 offset:640" : "=v"(r11) : "v"(ta));
    asm volatile("ds_read_b64_tr_b16 %0, %1 offset:256" : "=v"(r20) : "v"(ta));
    asm volatile("ds_read_b64_tr_b16 %0, %1 offset:768" : "=v"(r21) : "v"(ta));
    asm volatile("ds_read_b64_tr_b16 %0, %1 offset:384" : "=v"(r30) : "v"(ta));
    asm volatile("ds_read_b64_tr_b16 %0, %1 offset:896" : "=v"(r31) : "v"(ta));
    asm volatile("s_waitcnt lgkmcnt(0)" ::: "memory");
    __builtin_amdgcn_sched_barrier(0);

    fragU fa;
    fa.q[0] = r00; fa.q[1] = r01;
    acc[0][0] = __builtin_amdgcn_mfma_f32_16x16x32_bf16(fa.v, fb0.v, acc[0][0], 0, 0, 0);
    acc[0][1] = __builtin_amdgcn_mfma_f32_16x16x32_bf16(fa.v, fb1.v, acc[0][1], 0, 0, 0);
    fa.q[0] = r10; fa.q[1] = r11;
    acc[1][0] = __builtin_amdgcn_mfma_f32_16x16x32_bf16(fa.v, fb0.v, acc[1][0], 0, 0, 0);
    acc[1][1] = __builtin_amdgcn_mfma_f32_16x16x32_bf16(fa.v, fb1.v, acc[1][1], 0, 0, 0);
    fa.q[0] = r20; fa.q[1] = r21;
    acc[2][0] = __builtin_amdgcn_mfma_f32_16x16x32_bf16(fa.v, fb0.v, acc[2][0], 0, 0, 0);
    acc[2][1] = __builtin_amdgcn_mfma_f32_16x16x32_bf16(fa.v, fb1.v, acc[2][1], 0, 0, 0);
    fa.q[0] = r30; fa.q[1] = r31;
    acc[3][0] = __builtin_amdgcn_mfma_f32_16x16x32_bf16(fa.v, fb0.v, acc[3][0], 0, 0, 0);
    acc[3][1] = __builtin_amdgcn_mfma_f32_16x16x32_bf16(fa.v, fb1.v, acc[3][1], 0, 0, 0);
    __syncthreads();
  }

  if (t < 4) {
    ushort_t* dst = (t < 2) ? lidQK : camQK;
    const int colbase = (t & 1) * 128 + w * 32 + lane15;
    #pragma unroll
    for (int q = 0; q < 4; ++q)
      #pragma unroll
      for (int tt = 0; tt < 2; ++tt)
        #pragma unroll
        for (int r = 0; r < 4; ++r) {
          int n = y * 64 + q * 16 + g * 4 + r;
          dst[(size_t)n * 256 + colbase + tt * 16] = f2bf(acc[q][tt][r]);
        }
  } else {
    ushort_t* dst = (t == 4) ? camV : lidV;
    ushort_t* pout = dst + (size_t)(w * 32 + lane15) * 4096 + y * 64 + g * 4;
    #pragma unroll
    for (int q = 0; q < 4; ++q) {
      ushort4 p0, p1;
      p0.x = f2bf(acc[q][0][0]); p0.y = f2bf(acc[q][0][1]);
      p0.z = f2bf(acc[q][0][2]); p0.w = f2bf(acc[q][0][3]);
      p1.x = f2bf(acc[q][1][0]); p1.y = f2bf(acc[q][1][1]);
      p1.z = f2bf(acc[q][1][2]); p1.w = f2bf(acc[q][1][3]);
      *(ushort4*)(pout + q * 16)             = p0;
      *(ushort4*)(pout + 16 * 4096 + q * 16) = p1;
    }
  }
}

// ---------------------------------------------------------------------------
// flash attention: static-max 32x32 MFMA structure, key-split x2 (the
// best-measured configuration). In-register P via cvt_pk+permlane32_swap;
// row-sum on the MFMA pipe via ones-column; no online-max machinery.
// grid (32 qblk, 4 h, 4 = attn*2+half), block 256 = 4 waves x 32 q-rows.
// ---------------------------------------------------------------------------
__global__ __launch_bounds__(256) void flash_attn_mfma(
    const ushort_t* __restrict__ lidQK, const ushort_t* __restrict__ camQK,
    const ushort_t* __restrict__ camV, const ushort_t* __restrict__ lidV,
    ushort_t* __restrict__ OP, float2* __restrict__ ML) {
  const int i0    = blockIdx.x * 128;
  const int h     = blockIdx.y;
  const int attn  = blockIdx.z >> 1;
  const int half  = blockIdx.z & 1;
  const int kbase = half * 2048;
  const ushort_t* QK = attn ? camQK : lidQK;

  __shared__ __align__(16) ushort_t Ks[2][64 * 40];   // [k][32d], 80B rows
  __shared__ __align__(16) ushort_t Vt[2][64 * 72];   // [tensor*32+d][64k], 144B rows

  const int tid = threadIdx.x;
  const int w = tid >> 6, l = tid & 63;
  const int q31 = l & 31, hi = l >> 5;
  const int q0w = i0 + w * 32;

  const int srow = tid >> 2, sc = tid & 3;
  const ushort_t* Kg = QK + (size_t)(kbase + srow) * 256 + 128 + h * 32 + sc * 8;
  const ushort_t* Vg = ((srow >> 5) ? lidV : camV)
                     + (size_t)(h * 32 + (srow & 31)) * N_PIX + kbase;

  fragU qf0, qf1;
  qf0.u4 = *(const uint4*)(QK + (size_t)(q0w + q31) * 256 + h * 32 + hi * 8);
  qf1.u4 = *(const uint4*)(QK + (size_t)(q0w + q31) * 256 + h * 32 + 16 + hi * 8);

  { // prologue staging
    uint4 k4 = *(const uint4*)Kg;
    uint4 va = *(const uint4*)(Vg + sc * 8);
    uint4 vb = *(const uint4*)(Vg + (sc + 4) * 8);
    *(uint4*)(&Ks[0][srow * 40 + sc * 8]) = k4;
    *(uint4*)(&Vt[0][srow * 72 + sc * 8]) = va;
    *(uint4*)(&Vt[0][srow * 72 + (sc + 4) * 8]) = vb;
  }
  __syncthreads();

  fragU ones;
  #pragma unroll
  for (int j = 0; j < 8; ++j) ones.us[j] = 0x3F80;   // bf16 1.0

  f32x16 Oc = (f32x16)0.f, Ol = (f32x16)0.f, lacc = (f32x16)0.f;
  const f32x16 z16 = (f32x16)0.f;                     // loop-invariant C=0

  for (int it = 0; it < 32; ++it) {
    const int cur = it & 1, nxt = cur ^ 1;
    const bool more = (it + 1) < 32;
    uint4 kn, van, vbn;
    if (more) {
      kn  = *(const uint4*)(Kg + (size_t)(it + 1) * 16384);
      van = *(const uint4*)(Vg + (it + 1) * 64 + sc * 8);
      vbn = *(const uint4*)(Vg + (it + 1) * 64 + (sc + 4) * 8);
    }

    // ---- QK: S^T (2 k-tiles x 2 d-slices) ----
    const ushort_t* kb = &Ks[cur][0];
    fragU k00, k01, k10, k11;
    k00.u4 = *(const uint4*)(kb + q31 * 40 + hi * 8);
    k01.u4 = *(const uint4*)(kb + q31 * 40 + 16 + hi * 8);
    k10.u4 = *(const uint4*)(kb + (32 + q31) * 40 + hi * 8);
    k11.u4 = *(const uint4*)(kb + (32 + q31) * 40 + 16 + hi * 8);
    f32x16 S0, S1;
    __builtin_amdgcn_s_setprio(1);
    S0 = __builtin_amdgcn_mfma_f32_32x32x16_bf16(k00.v, qf0.v, z16, 0, 0, 0);
    S0 = __builtin_amdgcn_mfma_f32_32x32x16_bf16(k01.v, qf1.v, S0, 0, 0, 0);
    S1 = __builtin_amdgcn_mfma_f32_32x32x16_bf16(k10.v, qf0.v, z16, 0, 0, 0);
    S1 = __builtin_amdgcn_mfma_f32_32x32x16_bf16(k11.v, qf1.v, S1, 0, 0, 0);
    __builtin_amdgcn_s_setprio(0);

    // ---- static-max softmax: P = exp2(S) directly ----
    #pragma unroll
    for (int j = 0; j < 16; ++j) S0[j] = __builtin_amdgcn_exp2f(S0[j]);
    #pragma unroll
    for (int j = 0; j < 16; ++j) S1[j] = __builtin_amdgcn_exp2f(S1[j]);

    // ---- P -> A-frags: cvt_pk pairs + permlane32_swap ----
    fragU pa0, pa1, pa2, pa3;
    {
      unsigned a0, a1, b0, b1;
      asm("v_cvt_pk_bf16_f32 %0, %1, %2" : "=v"(a0) : "v"(S0[0]),  "v"(S0[1]));
      asm("v_cvt_pk_bf16_f32 %0, %1, %2" : "=v"(a1) : "v"(S0[2]),  "v"(S0[3]));
      asm("v_cvt_pk_bf16_f32 %0, %1, %2" : "=v"(b0) : "v"(S0[4]),  "v"(S0[5]));
      asm("v_cvt_pk_bf16_f32 %0, %1, %2" : "=v"(b1) : "v"(S0[6]),  "v"(S0[7]));
      uint2v r0 = __builtin_amdgcn_permlane32_swap(a0, b0, false, false);
      uint2v r1 = __builtin_amdgcn_permlane32_swap(a1, b1, false, false);
      pa0.u[0] = r0[0]; pa0.u[1] = r1[0]; pa0.u[2] = r0[1]; pa0.u[3] = r1[1];
      asm("v_cvt_pk_bf16_f32 %0, %1, %2" : "=v"(a0) : "v"(S0[8]),  "v"(S0[9]));
      asm("v_cvt_pk_bf16_f32 %0, %1, %2" : "=v"(a1) : "v"(S0[10]), "v"(S0[11]));
      asm("v_cvt_pk_bf16_f32 %0, %1, %2" : "=v"(b0) : "v"(S0[12]), "v"(S0[13]));
      asm("v_cvt_pk_bf16_f32 %0, %1, %2" : "=v"(b1) : "v"(S0[14]), "v"(S0[15]));
      r0 = __builtin_amdgcn_permlane32_swap(a0, b0, false, false);
      r1 = __builtin_amdgcn_permlane32_swap(a1, b1, false, false);
      pa1.u[0] = r0[0]; pa1.u[1] = r1[0]; pa1.u[2] = r0[1]; pa1.u[3] = r1[1];
      asm("v_cvt_pk_bf16_f32 %0, %1, %2" : "=v"(a0) : "v"(S1[0]),  "v"(S1[1]));
      asm("v_cvt_pk_bf16_f32 %0, %1, %2" : "=v"(a1) : "v"(S1[2]),  "v"(S1[3]));
      asm("v_cvt_pk_bf16_f32 %0, %1, %2" : "=v"(b0) : "v"(S1[4]),  "v"(S1[5]));
      asm("v_cvt_pk_bf16_f32 %0, %1, %2" : "=v"(b1) : "v"(S1[6]),  "v"(S1[7]));
      r0 = __builtin_amdgcn_permlane32_swap(a0, b0, false, false);
      r1 = __builtin_amdgcn_permlane32_swap(a1, b1, false, false);
      pa2.u[0] = r0[0]; pa2.u[1] = r1[0]; pa2.u[2] = r0[1]; pa2.u[3] = r1[1];
      asm("v_cvt_pk_bf16_f32 %0, %1, %2" : "=v"(a0) : "v"(S1[8]),  "v"(S1[9]));
      asm("v_cvt_pk_bf16_f32 %0, %1, %2" : "=v"(a1) : "v"(S1[10]), "v"(S1[11]));
      asm("v_cvt_pk_bf16_f32 %0, %1, %2" : "=v"(b0) : "v"(S1[12]), "v"(S1[13]));
      asm("v_cvt_pk_bf16_f32 %0, %1, %2" : "=v"(b1) : "v"(S1[14]), "v"(S1[15]));
      r0 = __builtin_amdgcn_permlane32_swap(a0, b0, false, false);
      r1 = __builtin_amdgcn_permlane32_swap(a1, b1, false, false);
      pa3.u[0] = r0[0]; pa3.u[1] = r1[0]; pa3.u[2] = r0[1]; pa3.u[3] = r1[1];
    }

    // ---- PV: 4 k-slices x 2 tensors + row-sum via ones-MFMA ----
    const ushort_t* vb = &Vt[cur][0];
    __builtin_amdgcn_s_setprio(1);
    {
      fragU vc, vl;
      vc.u4 = *(const uint4*)(vb + q31 * 72 + hi * 8);
      vl.u4 = *(const uint4*)(vb + (32 + q31) * 72 + hi * 8);
      Oc = __builtin_amdgcn_mfma_f32_32x32x16_bf16(pa0.v, vc.v, Oc, 0, 0, 0);
      Ol = __builtin_amdgcn_mfma_f32_32x32x16_bf16(pa0.v, vl.v, Ol, 0, 0, 0);
      lacc = __builtin_amdgcn_mfma_f32_32x32x16_bf16(pa0.v, ones.v, lacc, 0, 0, 0);
      vc.u4 = *(const uint4*)(vb + q31 * 72 + 16 + hi * 8);
      vl.u4 = *(const uint4*)(vb + (32 + q31) * 72 + 16 + hi * 8);
      Oc = __builtin_amdgcn_mfma_f32_32x32x16_bf16(pa1.v, vc.v, Oc, 0, 0, 0);
      Ol = __builtin_amdgcn_mfma_f32_32x32x16_bf16(pa1.v, vl.v, Ol, 0, 0, 0);
      lacc = __builtin_amdgcn_mfma_f32_32x32x16_bf16(pa1.v, ones.v, lacc, 0, 0, 0);
      vc.u4 = *(const uint4*)(vb + q31 * 72 + 32 + hi * 8);
      vl.u4 = *(const uint4*)(vb + (32 + q31) * 72 + 32 + hi * 8);
      Oc = __builtin_amdgcn_mfma_f32_32x32x16_bf16(pa2.v, vc.v, Oc, 0, 0, 0);
      Ol = __builtin_amdgcn_mfma_f32_32x32x16_bf16(pa2.v, vl.v, Ol, 0, 0, 0);
      lacc = __builtin_amdgcn_mfma_f32_32x32x16_bf16(pa2.v, ones.v, lacc, 0, 0, 0);
      vc.u4 = *(const uint4*)(vb + q31 * 72 + 48 + hi * 8);
      vl.u4 = *(const uint4*)(vb + (32 + q31) * 72 + 48 + hi * 8);
      Oc = __builtin_amdgcn_mfma_f32_32x32x16_bf16(pa3.v, vc.v, Oc, 0, 0, 0);
      Ol = __builtin_amdgcn_mfma_f32_32x32x16_bf16(pa3.v, vl.v, Ol, 0, 0, 0);
      lacc = __builtin_amdgcn_mfma_f32_32x32x16_bf16(pa3.v, ones.v, lacc, 0, 0, 0);
    }
    __builtin_amdgcn_s_setprio(0);

    if (more) {
      *(uint4*)(&Ks[nxt][srow * 40 + sc * 8]) = kn;
      *(uint4*)(&Vt[nxt][srow * 72 + sc * 8]) = van;
      *(uint4*)(&Vt[nxt][srow * 72 + (sc + 4) * 8]) = vbn;
    }
    __syncthreads();
  }

  // epilogue: unnormalized bf16 partials; rows q = crow(reg,hi).
  // lacc[reg] = row-sum (uniform across cols). ML.x = 0 (static max).
  ushort_t* OPc = OP + (size_t)((attn * 2 + half) * 2 + 0) * 4096 * 128;
  ushort_t* OPl = OP + (size_t)((attn * 2 + half) * 2 + 1) * 4096 * 128;
  const int d = h * 32 + q31;
  #pragma unroll
  for (int reg = 0; reg < 16; ++reg) {
    int n = q0w + (reg & 3) + 8 * (reg >> 2) + 4 * hi;
    OPc[(size_t)n * 128 + d] = f2bf(Oc[reg]);
    OPl[(size_t)n * 128 + d] = f2bf(Ol[reg]);
  }
  if (q31 == 0) {
    #pragma unroll
    for (int reg = 0; reg < 16; ++reg) {
      int n = q0w + (reg & 3) + 8 * (reg >> 2) + 4 * hi;
      float2 v; v.x = 0.f; v.y = lacc[reg];
      ML[(size_t)(attn * 2 + half) * 4096 + n] = v;
    }
  }
}

// ---------------------------------------------------------------------------
// proj_mfma: 2-way key-split combine + projection GEMM + residual + bias
// -> padded bf16 fuser-conv inputs. grid (64 nblk, 4 ot), block 256.
// Residuals read from bf16 mirrors (camBF / lidBF). Static max => weights
// are 1/(la+lb) directly.
// ---------------------------------------------------------------------------
__global__ __launch_bounds__(256) void proj_mfma_k(
    const ushort_t* __restrict__ OP, const float2* __restrict__ ML,
    const ushort_t* __restrict__ Wlid, const ushort_t* __restrict__ Wcam,
    const ushort_t* __restrict__ camBF, const ushort_t* __restrict__ lidBF,
    const float* __restrict__ cam_proj_b, const float* __restrict__ lid_proj_b,
    ushort_t* __restrict__ fm, ushort_t* __restrict__ fh) {
  const int n0 = blockIdx.x * 64;
  const int ot = blockIdx.y;
  const int attn = (ot == 0 || ot == 2) ? 1 : 0;
  const int vt = ot >> 1;
  const int tid = threadIdx.x;
  const int w = tid >> 6, l = tid & 63;
  const int m = l & 15, g = l >> 4;

  const ushort_t* Oa = OP + (size_t)((attn * 2 + 0) * 2 + vt) * 4096 * 128;
  const ushort_t* Ob = OP + (size_t)((attn * 2 + 1) * 2 + vt) * 4096 * 128;
  const float2* MLa = ML + (size_t)(attn * 2 + 0) * 4096;
  const float2* MLb = ML + (size_t)(attn * 2 + 1) * 4096;

  const int arow = n0 + w * 16 + m;
  float2 mla = MLa[arow], mlb = MLb[arow];
  float inv = 1.0f / (mla.y + mlb.y);   // static max: both m == 0

  fragU afr[4];
  #pragma unroll
  for (int s = 0; s < 4; ++s) {
    fragU xa, xb;
    xa.u4 = *(const uint4*)(Oa + (size_t)arow * 128 + s * 32 + g * 8);
    xb.u4 = *(const uint4*)(Ob + (size_t)arow * 128 + s * 32 + g * 8);
    #pragma unroll
    for (int j = 0; j < 8; ++j)
      afr[s].us[j] = f2bf(inv * (bf2f(xa.us[j]) + bf2f(xb.us[j])));
  }

  const ushort_t* W = (ot == 1) ? Wcam : Wlid;
  f32x4 acc[8];
  #pragma unroll
  for (int t = 0; t < 8; ++t) acc[t] = (f32x4){0.f, 0.f, 0.f, 0.f};
  #pragma unroll
  for (int s = 0; s < 4; ++s) {
    #pragma unroll
    for (int t = 0; t < 8; ++t) {
      fragU bfr;
      bfr.u4 = *(const uint4*)(W + (size_t)(t * 16 + m) * 128 + s * 32 + g * 8);
      acc[t] = __builtin_amdgcn_mfma_f32_16x16x32_bf16(afr[s].v, bfr.v, acc[t], 0, 0, 0);
    }
  }

  const float* bias = (ot == 1) ? cam_proj_b : lid_proj_b;
  const ushort_t* resBF = (ot < 2) ? camBF : lidBF;
  const int doff = ot * 126;
  #pragma unroll
  for (int t = 0; t < 8; ++t) {
    int co = t * 16 + m;
    if (co < 126) {
      float b = bias[co];
      #pragma unroll
      for (int r = 0; r < 4; ++r) {
        int n = n0 + w * 16 + g * 4 + r;
        float res = bf2f(resBF[(size_t)co * N_PIX + n]);
        float v = acc[t][r] + res + b;
        unsigned short bf = f2bf(v);
        int y = n >> 6, x = n & 63;
        fm[(doff + co) * 4224 + (y + 1) * 64 + x]      = bf;
        fh[(doff + co) * 4356 + (y + 1) * 66 + x + 1]  = bf;
      }
    }
  }
}

// ---------------------------------------------------------------------------
extern "C" void kernel_launch(void* const* d_in, const int* in_sizes, int n_in,
                              void* d_out, int out_size, void* d_ws, size_t ws_size,
                              hipStream_t stream) {
  (void)in_sizes; (void)n_in; (void)out_size; (void)ws_size;
  const float* lidar_bev  = (const float*)d_in[0];
  const float* cam_bev    = (const float*)d_in[1];
  const float* cam_enc_w  = (const float*)d_in[2];
  const float* cam_enc_b  = (const float*)d_in[3];
  const float* cam_v_w    = (const float*)d_in[4];
  const float* cam_qk_w   = (const float*)d_in[5];
  const float* cam_proj_w = (const float*)d_in[6];
  const float* cam_proj_b = (const float*)d_in[7];
  const float* lid_v_w    = (const float*)d_in[8];
  const float* lid_qk_w   = (const float*)d_in[9];
  const float* lid_proj_w = (const float*)d_in[10];
  const float* lid_proj_b = (const float*)d_in[11];
  const float* fuser_w    = (const float*)d_in[12];
  float* out = (float*)d_out;

  char* p = (char*)d_ws;
  // [0, 9437184): arena = 9 conv-tap partial slices (conv phases).
  // During attention: OP = 8 slices [0, 8MB), ML at [8MB, 8MB+128KB).
  ushort_t* arena = (ushort_t*)p;
  ushort_t* OP    = (ushort_t*)p;
  float2*   ML    = (float2*)(p + 8388608);
  ushort_t* lidQK = (ushort_t*)(p + 9437184);      // [4096][256] bf16
  ushort_t* camQK = (ushort_t*)(p + 11534336);
  ushort_t* camV  = (ushort_t*)(p + 13631488);     // [128][4096] bf16
  ushort_t* lidV  = (ushort_t*)(p + 14680064);
  ushort_t* Wp_c    = (ushort_t*)(p + 17793024);   // [9][128][96]
  ushort_t* Wp_f    = (ushort_t*)(p + 18014208);   // [9][128][512]
  ushort_t* Wp_lid  = (ushort_t*)(p + 19193856);   // [128][128]
  ushort_t* Wp_cam  = (ushort_t*)(p + 19226624);   // [128][128]
  ushort_t* Wq      = (ushort_t*)(p + 19259392);   // [6][128][128]
  ushort_t* lidBF   = (ushort_t*)(p + 19456000);   // [128][4096] (126 used)
  ushort_t* camBF   = (ushort_t*)(p + 20504576);   // [128][4096] bf16 cam_enc (persists)
  ushort_t* camBF_m = (ushort_t*)(p + 21553152);   // [96][66][64]
  ushort_t* camBF_h = (ushort_t*)(p + 22364160);   // [96][66][66]
  ushort_t* fusBF_m = (ushort_t*)(p + 23200512);   // [512][66][64]
  ushort_t* fusBF_h = (ushort_t*)(p + 27525888);   // [512][66][66] (end 31986432)

  zero_span_k<<<2548, 256, 0, stream>>>((uint4*)(p + 21553152), 652080);
  prep_k<<<6544, 256, 0, stream>>>(cam_enc_w, fuser_w, lid_proj_w, cam_proj_w,
                                   lid_qk_w, cam_qk_w, cam_v_w, lid_v_w,
                                   cam_bev, lidar_bev,
                                   Wp_c, Wp_f, Wp_lid, Wp_cam, Wq,
                                   camBF_m, camBF_h, lidBF);

  conv_mfma_k<<<dim3(64, 9), 256, 0, stream>>>(camBF_m, camBF_h, Wp_c, arena, 96, 3);
  reduce9_k<<<dim3(2, 126), 256, 0, stream>>>(arena, nullptr, camBF, cam_enc_b);

  qkv_mfma_k<<<dim3(64, 6), 256, 0, stream>>>(lidBF, camBF, Wq, lidQK, camQK, camV, lidV);
  flash_attn_mfma<<<dim3(32, 4, 4), 256, 0, stream>>>(lidQK, camQK, camV, lidV, OP, ML);
  proj_mfma_k<<<dim3(64, 4), 256, 0, stream>>>(OP, ML, Wp_lid, Wp_cam, camBF, lidBF,
                                               cam_proj_b, lid_proj_b, fusBF_m, fusBF_h);

  conv_mfma_k<<<dim3(64, 9), 256, 0, stream>>>(fusBF_m, fusBF_h, Wp_f, arena, 512, 16);
  reduce9_k<<<dim3(2, 126), 256, 0, stream>>>(arena, out, nullptr, nullptr);
}